// Round 13
// baseline (814.419 us; speedup 1.0000x reference)
//
#include <hip/hip_runtime.h>

#define TT 2048     // sequence length
#define DD 256      // head dim
#define RQB 128     // q-rows per block
#define NT 1024     // 16 waves: 4 row-groups (32 rows) x 4 col-quarters (512 cols)
#define NITER 24
#define CAPW 16     // per-wave per-row screen slots (E ~6 per 512-col quarter)
#define CAP2 16     // merged+filtered candidates per row (E ~3)
#define SLACK 1.6f

// LDS byte layout
#define L_CW   0                             // int [16][32] = 2 KB
#define L_IW   2048                          // u16 [512][CAPW] = 16 KB
#define L_SV   18432                         // f32 [512][CAPW] = 32 KB
#define L_CIDX 51200                         // u16 [128][CAP2] = 4 KB
#define L_CVAL 55296                         // f32 [128][CAP2] = 8 KB
#define L_CNT  63488                         // int [128]
#define L_SLOT 64000                         // u16 [16][128] = 4 KB
#define L_FBZ  68096                         // f32 [2048] = 8 KB (slow path)
#define L_OVF  76288
#define LDS_SZ 76304                         // ~74.5 KB -> 1 block/CU

typedef __attribute__((ext_vector_type(4))) float f32x4;
typedef __attribute__((ext_vector_type(8))) short short8;

__device__ inline unsigned short f2bf(float x) {     // RTN fp32 -> bf16
    unsigned u = __float_as_uint(x);
    return (unsigned short)((u + 0x7fffu + ((u >> 16) & 1u)) >> 16);
}

// max over each 16-lane group via DPP (VALU-only)
__device__ __forceinline__ float dppmax16(float m) {
    int a = __builtin_amdgcn_update_dpp(__float_as_int(m), __float_as_int(m),
                                        0xB1, 0xF, 0xF, false);   // quad_perm [1,0,3,2]
    m = fmaxf(m, __int_as_float(a));
    a = __builtin_amdgcn_update_dpp(__float_as_int(m), __float_as_int(m),
                                    0x4E, 0xF, 0xF, false);       // quad_perm [2,3,0,1]
    m = fmaxf(m, __int_as_float(a));
    a = __builtin_amdgcn_update_dpp(__float_as_int(m), __float_as_int(m),
                                    0x141, 0xF, 0xF, false);      // row_half_mirror
    m = fmaxf(m, __int_as_float(a));
    a = __builtin_amdgcn_update_dpp(__float_as_int(m), __float_as_int(m),
                                    0x140, 0xF, 0xF, false);      // row_mirror
    m = fmaxf(m, __int_as_float(a));
    return m;
}

// ---------------- pack K into MFMA-fragment order (0.5*K bf16) ----------------
__global__ __launch_bounds__(256) void pack_k_kernel(const float* __restrict__ K,
        unsigned short* __restrict__ Khf) {
    const int t = blockIdx.x * 256 + threadIdx.x;
    const int lane = t & 63;
    const int kk = (t >> 6) & 7;
    const int g  = (t >> 9) & 127;
    const int b  = t >> 16;
    const int col = g * 16 + (lane & 15);
    const int d0  = kk * 32 + (lane >> 4) * 8;
    const float* src = K + ((size_t)b * TT + col) * DD + d0;
    const float4 f0 = *(const float4*)(src);
    const float4 f1 = *(const float4*)(src + 4);
    uint4 pk;
    pk.x = (unsigned)f2bf(0.5f * f0.x) | ((unsigned)f2bf(0.5f * f0.y) << 16);
    pk.y = (unsigned)f2bf(0.5f * f0.z) | ((unsigned)f2bf(0.5f * f0.w) << 16);
    pk.z = (unsigned)f2bf(0.5f * f1.x) | ((unsigned)f2bf(0.5f * f1.y) << 16);
    pk.w = (unsigned)f2bf(0.5f * f1.z) | ((unsigned)f2bf(0.5f * f1.w) << 16);
    *(uint4*)(Khf + (size_t)t * 8) = pk;
}

// ---------------- main fused kernel (barrier-free sweep) ----------------
#define LOADB(B_, g_) do { \
    _Pragma("unroll") for (int kk_ = 0; kk_ < 8; ++kk_) \
        B_[kk_] = *(const short8*)(KfB + ((size_t)((Gbase + (g_)) * 8 + kk_) << 10) + lane * 16); \
    } while (0)

#define PROCF(B_, aA_, aB_) do { \
    _Pragma("unroll") for (int r_ = 0; r_ < 4; ++r_) { aA_[r_] = 0.0f; aB_[r_] = 0.0f; } \
    _Pragma("unroll") for (int kk_ = 0; kk_ < 8; ++kk_) { \
        aA_ = __builtin_amdgcn_mfma_f32_16x16x32_bf16(ah0[kk_], B_[kk_], aA_, 0, 0, 0); \
        aB_ = __builtin_amdgcn_mfma_f32_16x16x32_bf16(ah1[kk_], B_[kk_], aB_, 0, 0, 0); \
    } } while (0)

__launch_bounds__(NT, 4)
__global__ void entmax_frag_kernel(const float* __restrict__ Q,
                                   const unsigned short* __restrict__ Khf,
                                   const float* __restrict__ Kf,
                                   const float* __restrict__ V,
                                   float* __restrict__ Out,
                                   int nwg) {
    extern __shared__ char smem[];
    int*            CW   = (int*)(smem + L_CW);
    unsigned short* IW   = (unsigned short*)(smem + L_IW);
    float*          SV   = (float*)(smem + L_SV);
    unsigned short* CIDX = (unsigned short*)(smem + L_CIDX);
    float*          CVAL = (float*)(smem + L_CVAL);
    int*            CNT  = (int*)(smem + L_CNT);
    unsigned short* SLOT = (unsigned short*)(smem + L_SLOT);
    int*            POVF = (int*)(smem + L_OVF);

    const int tid = threadIdx.x;
    const int wid = tid >> 6, lane = tid & 63;
    const int l15 = lane & 15, ag = lane >> 4;
    const int rg = wid >> 2, cg = wid & 3;   // 32-row group, 512-col quarter
    const int wrow0 = wid * 8;               // tail ownership: 8 rows/wave

    // XCD-bijective swizzle (nwg = B*16 = 256)
    const int lb = (blockIdx.x & 7) * (nwg >> 3) + (blockIdx.x >> 3);
    const int b  = lb >> 4;
    const int t0 = (lb & 15) * RQB;

    const char* KfB = (const char*)Khf + (size_t)b * 1048576;   // 128 g x 8 kk x 1024 B
    const int Gbase = cg * 32;
    const int colw0 = cg * 512;

    if (tid < 512) CW[tid] = 0;
    if (tid == 0) *POVF = 0;

    // ---- A-fragments: 32 rows per wave in VGPRs ----
    short8 ah0[8], ah1[8];
    {
        const float* q0 = Q + (size_t)(b * TT + t0 + rg * 32 + l15) * DD;
        const float* q1 = q0 + 16 * DD;
        #pragma unroll
        for (int kk = 0; kk < 8; ++kk) {
            const int d0 = kk * 32 + ag * 8;
            float4 a = *(const float4*)(q0 + d0);
            float4 c = *(const float4*)(q0 + d0 + 4);
            float qf[8] = {a.x, a.y, a.z, a.w, c.x, c.y, c.z, c.w};
            #pragma unroll
            for (int i = 0; i < 8; ++i) ah0[kk][i] = (short)f2bf(qf[i]);
            a = *(const float4*)(q1 + d0);
            c = *(const float4*)(q1 + d0 + 4);
            float qg[8] = {a.x, a.y, a.z, a.w, c.x, c.y, c.z, c.w};
            #pragma unroll
            for (int i = 0; i < 8; ++i) ah1[kk][i] = (short)f2bf(qg[i]);
        }
    }

    const unsigned long long grpmask = 0xFFFFULL << (ag * 16);
    const unsigned long long lowmask = (lane == 0) ? 0ULL : ((~0ULL) >> (64 - lane));
    float rm0[4], rm1[4];
    int   bs0[4], bs1[4];
    #pragma unroll
    for (int r = 0; r < 4; ++r) {
        rm0[r] = -3.0e30f; rm1[r] = -3.0e30f;
        bs0[r] = 0; bs1[r] = 0;
    }

    // screen 4 chunk-accumulators for one 16-row fragment set
    auto screen4 = [&](float (&rm)[4], int (&bs)[4], int fof,
                       const f32x4& x0, const f32x4& x1,
                       const f32x4& x2, const f32x4& x3, int c0) {
        #pragma unroll
        for (int r = 0; r < 4; ++r) {
            float m = fmaxf(fmaxf(x0[r], x1[r]), fmaxf(x2[r], x3[r]));
            m = dppmax16(m);
            rm[r] = fmaxf(rm[r], m);
            const float thr = rm[r] - SLACK;
            if (m > thr) {                       // group-uniform early-out
                const int lrow = wid * 32 + fof + ag * 4 + r;
                const float vals[4] = {x0[r], x1[r], x2[r], x3[r]};
                #pragma unroll
                for (int ch = 0; ch < 4; ++ch) {
                    const bool p = vals[ch] > thr;
                    const unsigned long long ba = __ballot(p) & grpmask;
                    if (ba) {
                        const int rk = (int)__popcll(ba & lowmask);
                        if (p && bs[r] + rk < CAPW) {
                            IW[lrow * CAPW + bs[r] + rk] =
                                (unsigned short)(colw0 + (c0 + ch) * 16 + l15);
                            SV[lrow * CAPW + bs[r] + rk] = vals[ch];
                        }
                        bs[r] += (int)__popcll(ba);
                    }
                }
            }
        }
    };

    // ---------------- barrier-free sweep: 8 groups x 4 chunks x 16 cols ----------------
    short8 B0[8], B1[8];
    for (int j = 0; j < 8; ++j) {
        const int c0 = j * 4;
        f32x4 a0A, a0B, a1A, a1B, a2A, a2B, a3A, a3B;
        LOADB(B0, c0);
        LOADB(B1, c0 + 1);
        PROCF(B0, a0A, a0B);
        LOADB(B0, c0 + 2);
        PROCF(B1, a1A, a1B);
        LOADB(B1, c0 + 3);
        PROCF(B0, a2A, a2B);
        PROCF(B1, a3A, a3B);
        screen4(rm0, bs0, 0,  a0A, a1A, a2A, a3A, c0);
        screen4(rm1, bs1, 16, a0B, a1B, a2B, a3B, c0);
    }

    // publish per-wave counts
    if (l15 == 0) {
        #pragma unroll
        for (int r = 0; r < 4; ++r) {
            CW[wid * 32 + ag * 4 + r]      = bs0[r];
            CW[wid * 32 + 16 + ag * 4 + r] = bs1[r];
        }
    }
    __syncthreads();

    // ---------------- merge 4 quarters + screen-value filter (lane<8 owns a row) ----------------
    if (lane < 8) {
        const int R = wrow0 + lane;            // block-local row 0..127
        const int lr = R & 31;
        const int w0 = (R >> 5) << 2;
        int cws[4];
        float smax = -3.0e30f;
        int ovf = 0;
        #pragma unroll
        for (int q2 = 0; q2 < 4; ++q2) {
            int cw = CW[(w0 + q2) * 32 + lr];
            if (cw > CAPW) { ovf = 1; cw = CAPW; }
            cws[q2] = cw;
            for (int i = 0; i < cw; ++i)
                smax = fmaxf(smax, SV[((w0 + q2) * 32 + lr) * CAPW + i]);
        }
        const float fthr = smax - SLACK;       // exact-max candidates guaranteed kept
        int n2 = 0;
        #pragma unroll
        for (int q2 = 0; q2 < 4; ++q2) {
            for (int i = 0; i < cws[q2]; ++i) {
                const float v = SV[((w0 + q2) * 32 + lr) * CAPW + i];
                if (v > fthr) {
                    if (n2 < CAP2)
                        CIDX[R * CAP2 + n2] = IW[((w0 + q2) * 32 + lr) * CAPW + i];
                    ++n2;
                }
            }
        }
        if (n2 > CAP2) ovf = 1;
        CNT[R] = ovf ? (CAP2 + 1) : n2;
        if (ovf) *POVF = 1;
    }

    // ---------------- exact fp32 recompute of filtered candidates (wave-local) ----------------
    int c = 0;
    if (lane < 8) {
        const int cc = CNT[wrow0 + lane];
        c = (cc > CAP2) ? 0 : cc;              // overflow rows -> slow path
    }
    int x = c;
    #pragma unroll
    for (int off = 1; off < 8; off <<= 1) {
        const int v = __shfl_up(x, off);
        if (lane >= off) x += v;
    }
    const int pfx = x - c;
    const int total = __shfl(x, 7);
    if (lane < 8)
        for (int i = 0; i < c; ++i)
            SLOT[wid * 128 + pfx + i] = (unsigned short)((lane << 8) | i);

    {
        const float* Qb = Q + (size_t)(b * TT + t0 + wrow0) * DD;
        const float* Kb = Kf + (size_t)b * TT * DD;
        for (int bsx = 0; bsx < total; bsx += 8) {
            float4 qv[8], kv[8];
            int rl[8], ii[8];
            #pragma unroll
            for (int u = 0; u < 8; ++u) {
                const int s = bsx + u;
                const int e = (s < total) ? (int)SLOT[wid * 128 + s] : 0;
                rl[u] = e >> 8; ii[u] = e & 255;
                const int col = (s < total) ? (int)CIDX[(wrow0 + rl[u]) * CAP2 + ii[u]] : 0;
                qv[u] = *(const float4*)(Qb + (size_t)rl[u] * DD + lane * 4);
                kv[u] = *(const float4*)(Kb + (size_t)col * DD + lane * 4);
            }
            float sm[8];
            #pragma unroll
            for (int u = 0; u < 8; ++u) {
                float d = qv[u].x * kv[u].x;
                d = fmaf(qv[u].y, kv[u].y, d);
                d = fmaf(qv[u].z, kv[u].z, d);
                d = fmaf(qv[u].w, kv[u].w, d);
                sm[u] = d;
            }
            #pragma unroll
            for (int off = 32; off; off >>= 1)
                #pragma unroll
                for (int u = 0; u < 8; ++u) sm[u] += __shfl_xor(sm[u], off);
            #pragma unroll
            for (int u = 0; u < 8; ++u)
                if (lane == u && bsx + u < total)
                    CVAL[(wrow0 + rl[u]) * CAP2 + ii[u]] = 0.5f * sm[u];
        }
    }
    __syncthreads();

    // ---------------- slow path (overflow; ~never) ----------------
    if (*POVF) {
        if (wid == 0) {
            float* fbz = (float*)(smem + L_FBZ);
            for (int r = 0; r < RQB; ++r) {
                if (CNT[r] <= CAP2) continue;
                const float* qr = Q + (size_t)(b * TT + t0 + r) * DD;
                const float* Kb = Kf + (size_t)b * TT * DD;
                for (int cc2 = lane; cc2 < TT; cc2 += 64) {
                    const float* kr = Kb + (size_t)cc2 * DD;
                    float a = 0.0f;
                    for (int d = 0; d < DD; ++d) a = fmaf(qr[d], kr[d], a);
                    fbz[cc2] = 0.5f * a;
                }
                __threadfence_block();
                float m = -3.402823466e38f;
                for (int cc2 = lane; cc2 < TT; cc2 += 64) m = fmaxf(m, fbz[cc2]);
                #pragma unroll
                for (int off = 32; off; off >>= 1) m = fmaxf(m, __shfl_xor(m, off));
                float lo = m - 1.0f, hi = m, tau;
                for (int it = 0; it < 30; ++it) {
                    tau = 0.5f * (lo + hi);
                    float s = 0.0f;
                    for (int cc2 = lane; cc2 < TT; cc2 += 64) {
                        const float tt2 = fmaxf(fbz[cc2] - tau, 0.0f);
                        s = fmaf(tt2, tt2, s);
                    }
                    #pragma unroll
                    for (int off = 32; off; off >>= 1) s += __shfl_xor(s, off);
                    const bool gt = s > 1.0f;
                    lo = gt ? tau : lo;
                    hi = gt ? hi : tau;
                }
                tau = 0.5f * (lo + hi);
                float ssum = 0.0f;
                for (int cc2 = lane; cc2 < TT; cc2 += 64) {
                    const float tt2 = fmaxf(fbz[cc2] - tau, 0.0f);
                    ssum = fmaf(tt2, tt2, ssum);
                }
                #pragma unroll
                for (int off = 32; off; off >>= 1) ssum += __shfl_xor(ssum, off);
                const float inv = 1.0f / ssum;
                const int d4 = lane * 4;
                float4 o = make_float4(0.f, 0.f, 0.f, 0.f);
                for (int s = 0; s < TT; ++s) {
                    const float tt2 = fmaxf(fbz[s] - tau, 0.0f);
                    const float w = tt2 * tt2 * inv;
                    if (w > 0.0f) {
                        const float4 v = *(const float4*)(V + ((size_t)b * TT + s) * DD + d4);
                        o.x = fmaf(w, v.x, o.x); o.y = fmaf(w, v.y, o.y);
                        o.z = fmaf(w, v.z, o.z); o.w = fmaf(w, v.w, o.w);
                    }
                }
                *(float4*)(Out + ((size_t)(b * TT + t0 + r)) * DD + d4) = o;
                if (lane == 0) CNT[r] = -1;
                __threadfence_block();
            }
        }
        __syncthreads();
    }

    // ---------------- scalar per-lane tau + weights (lane r owns row wrow0+r) ----------------
    {
        const int myrow = wrow0 + (lane & 7);
        const int nRaw = CNT[myrow];
        const int n = (nRaw < 0 || nRaw > CAP2) ? 0 : nRaw;
        float cvr[CAP2];
        #pragma unroll
        for (int i = 0; i < CAP2; ++i)
            cvr[i] = (i < n) ? CVAL[myrow * CAP2 + i] : -3.0e30f;
        float emax = cvr[0];
        #pragma unroll
        for (int i = 1; i < CAP2; ++i) emax = fmaxf(emax, cvr[i]);
        float lo = emax - 1.0f, hi = emax;
        for (int it = 0; it < NITER; ++it) {
            const float tau = 0.5f * (lo + hi);
            float s = 0.0f;
            #pragma unroll
            for (int i = 0; i < CAP2; ++i) {
                const float tt2 = fmaxf(cvr[i] - tau, 0.0f);
                s = fmaf(tt2, tt2, s);
            }
            const bool gt = s > 1.0f;
            lo = gt ? tau : lo;
            hi = gt ? hi : tau;
        }
        const float tau = 0.5f * (lo + hi);
        float ssum = 0.0f;
        #pragma unroll
        for (int i = 0; i < CAP2; ++i) {
            const float tt2 = fmaxf(cvr[i] - tau, 0.0f);
            ssum = fmaf(tt2, tt2, ssum);
        }
        const float inv = 1.0f / ssum;
        if (lane < 8 && n > 0) {
            for (int i = 0; i < n; ++i) {
                const float tt2 = fmaxf(cvr[i] - tau, 0.0f);
                CVAL[myrow * CAP2 + i] = tt2 * tt2 * inv;
            }
        }
    }

    // ---------------- sparse PV via broadcast LDS reads ----------------
    const float* Vb = V + (size_t)b * TT * DD;
    for (int j = 0; j < 8; ++j) {
        const int row = wrow0 + j;
        const int n = CNT[row];
        if (n < 0 || n > CAP2) continue;       // slow path handled
        const int d4 = lane * 4;
        float4 o = make_float4(0.f, 0.f, 0.f, 0.f);
        for (int i = 0; i < n; ++i) {
            const float wi = CVAL[row * CAP2 + i];
            if (wi > 0.0f) {
                const int si = (int)CIDX[row * CAP2 + i];
                const float4 v = *(const float4*)(Vb + (size_t)si * DD + d4);
                o.x = fmaf(wi, v.x, o.x); o.y = fmaf(wi, v.y, o.y);
                o.z = fmaf(wi, v.z, o.z); o.w = fmaf(wi, v.w, o.w);
            }
        }
        *(float4*)(Out + ((size_t)(b * TT + t0 + row)) * DD + d4) = o;
    }
}

// ---------------- round-1 kernel kept as ws-size fallback ----------------
#define DOT4(A, Kv, Qv) \
    A = fmaf((Qv).x, (Kv).x, fmaf((Qv).y, (Kv).y, fmaf((Qv).z, (Kv).z, fmaf((Qv).w, (Kv).w, (A)))))

__launch_bounds__(256, 2)
__global__ void entmax_fallback_kernel(const float* __restrict__ Q,
                                       const float* __restrict__ V,
                                       const float* __restrict__ K,
                                       float* __restrict__ Out) {
    extern __shared__ float zshf[];
    const int tid = threadIdx.x;
    const int b   = blockIdx.x >> 8;
    const int t0  = (blockIdx.x & 255) * 8;
    const float* Qb = Q + ((size_t)b * TT + t0) * DD;
    const float* Kb = K + (size_t)b * TT * DD;
    const float* Vb = V + (size_t)b * TT * DD;
    for (int g = 0; g < 2; ++g) {
        const int c0 = (g << 10) + tid;
        const float* k0 = Kb + (size_t)c0 * DD;
        float4 acc[8];
        #pragma unroll
        for (int r = 0; r < 8; ++r) acc[r] = make_float4(0.f, 0.f, 0.f, 0.f);
        for (int d = 0; d < DD; d += 4) {
            const float4 ka = *(const float4*)(k0 + d);
            const float4 kb = *(const float4*)(k0 + 256 * DD + d);
            const float4 kc = *(const float4*)(k0 + 512 * DD + d);
            const float4 kd = *(const float4*)(k0 + 768 * DD + d);
            #pragma unroll
            for (int r = 0; r < 8; ++r) {
                const float4 qv = *(const float4*)(Qb + r * DD + d);
                DOT4(acc[r].x, ka, qv); DOT4(acc[r].y, kb, qv);
                DOT4(acc[r].z, kc, qv); DOT4(acc[r].w, kd, qv);
            }
        }
        #pragma unroll
        for (int r = 0; r < 8; ++r) {
            zshf[r * TT + c0      ] = 0.5f * acc[r].x;
            zshf[r * TT + c0 + 256] = 0.5f * acc[r].y;
            zshf[r * TT + c0 + 512] = 0.5f * acc[r].z;
            zshf[r * TT + c0 + 768] = 0.5f * acc[r].w;
        }
    }
    __syncthreads();
    {
        const int wid = tid >> 6, lane = tid & 63;
        for (int rr = 0; rr < 2; ++rr) {
            const int r = wid * 2 + rr;
            float* z = zshf + r * TT;
            float zv[32];
            float m = -3.402823466e38f;
            #pragma unroll
            for (int j = 0; j < 32; ++j) { zv[j] = z[lane + (j << 6)]; m = fmaxf(m, zv[j]); }
            #pragma unroll
            for (int off = 32; off; off >>= 1) m = fmaxf(m, __shfl_xor(m, off));
            float lo = m - 1.0f, hi = m;
            for (int it = 0; it < 30; ++it) {
                const float tau = 0.5f * (lo + hi);
                float s = 0.f;
                #pragma unroll
                for (int j = 0; j < 32; ++j) { float t = fmaxf(zv[j] - tau, 0.f); s = fmaf(t, t, s); }
                #pragma unroll
                for (int off = 32; off; off >>= 1) s += __shfl_xor(s, off);
                const bool gt = (s - 1.0f) > 0.0f;
                lo = gt ? tau : lo; hi = gt ? hi : tau;
            }
            const float tau = 0.5f * (lo + hi);
            float ssum = 0.f;
            #pragma unroll
            for (int j = 0; j < 32; ++j) { float t = fmaxf(zv[j] - tau, 0.f); ssum = fmaf(t, t, ssum); }
            #pragma unroll
            for (int off = 32; off; off >>= 1) ssum += __shfl_xor(ssum, off);
            const float inv = 1.0f / ssum;
            #pragma unroll
            for (int j = 0; j < 32; ++j) {
                float t = fmaxf(zv[j] - tau, 0.f);
                z[lane + (j << 6)] = t * t * inv;
            }
        }
    }
    __syncthreads();
    {
        const int d2 = (tid & 127) * 2;
        const int sg = tid >> 7;
        float2 acc[8];
        #pragma unroll
        for (int r = 0; r < 8; ++r) acc[r] = make_float2(0.f, 0.f);
        for (int sc = 0; sc < TT; sc += 8) {
            const int s0 = sc + sg * 4;
            float4 w4[8];
            #pragma unroll
            for (int r = 0; r < 8; ++r) w4[r] = *(const float4*)&zshf[r * TT + s0];
            #pragma unroll
            for (int js = 0; js < 4; ++js) {
                const float2 v = *(const float2*)(Vb + (size_t)(s0 + js) * DD + d2);
                #pragma unroll
                for (int r = 0; r < 8; ++r) {
                    const float wv = (js == 0) ? w4[r].x : (js == 1) ? w4[r].y
                                   : (js == 2) ? w4[r].z : w4[r].w;
                    acc[r].x = fmaf(wv, v.x, acc[r].x);
                    acc[r].y = fmaf(wv, v.y, acc[r].y);
                }
            }
        }
        __syncthreads();
        float* part = zshf;
        if (sg == 1) {
            #pragma unroll
            for (int r = 0; r < 8; ++r) *(float2*)&part[r * DD + d2] = acc[r];
        }
        __syncthreads();
        if (sg == 0) {
            #pragma unroll
            for (int r = 0; r < 8; ++r) {
                const float2 p = *(const float2*)&part[r * DD + d2];
                float2 o; o.x = acc[r].x + p.x; o.y = acc[r].y + p.y;
                *(float2*)&Out[((size_t)b * TT + t0 + r) * DD + d2] = o;
            }
        }
    }
}

extern "C" void kernel_launch(void* const* d_in, const int* in_sizes, int n_in,
                              void* d_out, int out_size, void* d_ws, size_t ws_size,
                              hipStream_t stream) {
    const float* Q = (const float*)d_in[0];   // query
    const float* V = (const float*)d_in[1];   // value (dict order!)
    const float* K = (const float*)d_in[2];   // key
    float* Out = (float*)d_out;
    const int B = in_sizes[0] / (TT * DD);
    const size_t NE = (size_t)B * TT * DD;
    const size_t need = NE * 2;               // Khf bf16

    if (ws_size < need) {                     // defensive fallback (round-1 kernel)
        entmax_fallback_kernel<<<dim3(B * (TT / 8)), 256, 8 * TT * sizeof(float), stream>>>(
            Q, V, K, Out);
        return;
    }

    unsigned short* Khf = (unsigned short*)d_ws;
    pack_k_kernel<<<dim3(B * 256), 256, 0, stream>>>(K, Khf);

    const int nwg = B * (TT / RQB);           // 256 -> 1 block/CU, 16 waves
    (void)hipFuncSetAttribute((const void*)entmax_frag_kernel,
                              hipFuncAttributeMaxDynamicSharedMemorySize, LDS_SZ);
    entmax_frag_kernel<<<dim3(nwg), NT, LDS_SZ, stream>>>(Q, Khf, K, V, Out, nwg);
}

// Round 14
// 145.946 us; speedup vs baseline: 5.5803x; 5.5803x over previous
//
#include <hip/hip_runtime.h>

#define TT 2048     // sequence length
#define DD 256      // head dim
#define RQB 128     // q-rows per block (8 waves x 16)
#define NT 512      // 8 waves
#define KB 64       // K-cols per LDS tile (32 KB)
#define NTILE (TT / KB)   // 32
#define NITER 30
#define CAP 28      // stored candidates per row

// LDS byte layout (staging: 3 x 32 KB triple buffer at offset 0)
#define L_CIDX 98304                       // u16 [RQB][CAP] = 7 KB
#define L_CVAL (L_CIDX + RQB * CAP * 2)    // f32 [RQB][CAP] = 14 KB
#define L_CNT  (L_CVAL + RQB * CAP * 4)    // int [RQB]
#define L_SLOT (L_CNT + RQB * 4)           // u16 [8][16*CAP] = 7 KB
#define L_OVF  (L_SLOT + 8 * 16 * CAP * 2)
#define LDS_SZ (L_OVF + 16)                // ~124.5 KB -> 1 block/CU

typedef __attribute__((ext_vector_type(4))) float f32x4;
typedef __attribute__((ext_vector_type(8))) short short8;

__device__ inline unsigned short f2bf(float x) {     // RTN fp32 -> bf16
    unsigned u = __float_as_uint(x);
    return (unsigned short)((u + 0x7fffu + ((u >> 16) & 1u)) >> 16);
}

__device__ __forceinline__ void gload16(const void* g, void* l) {
    __builtin_amdgcn_global_load_lds(
        (const __attribute__((address_space(1))) void*)g,
        (__attribute__((address_space(3))) void*)l, 16, 0, 0);
}

// max over each 16-lane group via DPP (VALU-only, no LDS-pipe traffic)
__device__ __forceinline__ float dppmax16(float m) {
    int a = __builtin_amdgcn_update_dpp(__float_as_int(m), __float_as_int(m),
                                        0xB1, 0xF, 0xF, false);   // quad_perm [1,0,3,2]
    m = fmaxf(m, __int_as_float(a));
    a = __builtin_amdgcn_update_dpp(__float_as_int(m), __float_as_int(m),
                                    0x4E, 0xF, 0xF, false);       // quad_perm [2,3,0,1]
    m = fmaxf(m, __int_as_float(a));
    a = __builtin_amdgcn_update_dpp(__float_as_int(m), __float_as_int(m),
                                    0x141, 0xF, 0xF, false);      // row_half_mirror
    m = fmaxf(m, __int_as_float(a));
    a = __builtin_amdgcn_update_dpp(__float_as_int(m), __float_as_int(m),
                                    0x140, 0xF, 0xF, false);      // row_mirror
    m = fmaxf(m, __int_as_float(a));
    return m;
}

// ---------------- helper: K -> 0.5*K bf16 (screening operand) ----------------
__global__ __launch_bounds__(256) void split_k_kernel(const float* __restrict__ K,
        unsigned short* __restrict__ Kh, int n4) {
    int i = blockIdx.x * 256 + threadIdx.x;
    const int stride = gridDim.x * 256;
    for (; i < n4; i += stride) {
        float4 v = ((const float4*)K)[i];
        unsigned short h0 = f2bf(0.5f * v.x), h1 = f2bf(0.5f * v.y);
        unsigned short h2 = f2bf(0.5f * v.z), h3 = f2bf(0.5f * v.w);
        uint2 hv;
        hv.x = (unsigned)h0 | ((unsigned)h1 << 16);
        hv.y = (unsigned)h2 | ((unsigned)h3 << 16);
        ((uint2*)Kh)[i] = hv;
    }
}

// ---------------- main fused kernel ----------------
__launch_bounds__(NT, 2)
__global__ void entmax_screen_kernel(const float* __restrict__ Q,
                                     const unsigned short* __restrict__ Kh,
                                     const float* __restrict__ Kf,
                                     const float* __restrict__ V,
                                     float* __restrict__ Out,
                                     int nwg) {
    extern __shared__ char smem[];
    unsigned short* CIDX = (unsigned short*)(smem + L_CIDX);
    float*          CVAL = (float*)(smem + L_CVAL);
    int*            CNT  = (int*)(smem + L_CNT);
    unsigned short* SLOT = (unsigned short*)(smem + L_SLOT);
    int*            POVF = (int*)(smem + L_OVF);

    const int tid = threadIdx.x;
    const int wid = tid >> 6, lane = tid & 63;
    const int l15 = lane & 15, ag = lane >> 4;
    const int wrow0 = wid * 16;

    // XCD-bijective swizzle (nwg = B*16 = 256, divisible by 8)
    const int lb = (blockIdx.x & 7) * (nwg >> 3) + (blockIdx.x >> 3);
    const int b  = lb >> 4;
    const int t0 = (lb & 15) * RQB;

    const char* KhB = (const char*)(Kh + (size_t)b * TT * DD);

    if (tid == 0) *POVF = 0;

    // ---- A-fragments: 16 Q rows per wave, single bf16 ----
    short8 ah[8];
    {
        const float* qr = Q + (size_t)(b * TT + t0 + wrow0 + l15) * DD;
        #pragma unroll
        for (int kk = 0; kk < 8; ++kk) {
            const int d0 = kk * 32 + ag * 8;
            float4 qa = *(const float4*)(qr + d0);
            float4 qb = *(const float4*)(qr + d0 + 4);
            float qf[8] = {qa.x, qa.y, qa.z, qa.w, qb.x, qb.y, qb.z, qb.w};
            #pragma unroll
            for (int i = 0; i < 8; ++i) ah[kk][i] = (short)f2bf(qf[i]);
        }
    }

    // ---- hoisted staging offsets (4 x 1 KB per wave per 32 KB tile) ----
    int gofs[4], lofs[4];
    #pragma unroll
    for (int j = 0; j < 4; ++j) {
        const int ofs = wid * 4096 + j * 1024 + lane * 16;   // linear byte in tile
        const int cl = ofs >> 9, wb = ofs & 511;
        gofs[j] = cl * 512 + (wb ^ ((cl & 7) << 4));         // inverse-swizzled src
        lofs[j] = ofs;
    }
    auto STAGE = [&](int tile, int buf) {
        const size_t gt = (size_t)tile << 15;                // tile * 32768
        char* lb_ = smem + buf * 32768;
        #pragma unroll
        for (int j = 0; j < 4; ++j) gload16(KhB + gt + gofs[j], lb_ + lofs[j]);
    };

    // prologue: tiles 0 and 1 in flight; ensure 0 complete block-wide
    STAGE(0, 0);
    STAGE(1, 1);
    asm volatile("s_waitcnt vmcnt(4)" ::: "memory");
    __builtin_amdgcn_s_barrier();

    const unsigned long long grpmask = 0xFFFFULL << (ag * 16);
    const unsigned long long lowmask = (lane == 0) ? 0ULL : ((~0ULL) >> (64 - lane));
    float rmax[4];
    int   base[4];
    #pragma unroll
    for (int r = 0; r < 4; ++r) { rmax[r] = -3.402823466e38f; base[r] = 0; }

    // ---------------- screening sweep: 32 tiles of 64 cols, counted-vmcnt pipeline ----------------
    int bufc = 0;                            // t % 3
    for (int t = 0; t < NTILE; ++t) {
        if (t + 2 < NTILE) {
            int sb = bufc + 2; if (sb >= 3) sb -= 3;
            STAGE(t + 2, sb);
        }
        // compute tile t from buf[bufc]
        f32x4 acc[4];
        #pragma unroll
        for (int ct = 0; ct < 4; ++ct)
            #pragma unroll
            for (int r = 0; r < 4; ++r) acc[ct][r] = 0.0f;
        __builtin_amdgcn_s_setprio(1);
        #pragma unroll
        for (int kk = 0; kk < 8; ++kk) {
            short8 bh[4];
            #pragma unroll
            for (int ct = 0; ct < 4; ++ct)
                bh[ct] = *(const short8*)(smem + bufc * 32768 + (ct * 16 + l15) * 512 +
                                          (((kk * 64) + ag * 16) ^ ((l15 & 7) << 4)));
            #pragma unroll
            for (int ct = 0; ct < 4; ++ct)
                acc[ct] = __builtin_amdgcn_mfma_f32_16x16x32_bf16(ah[kk], bh[ct], acc[ct], 0, 0, 0);
        }
        __builtin_amdgcn_s_setprio(0);
        // per-row-group running max (DPP) + early-out candidate append
        #pragma unroll
        for (int rg = 0; rg < 4; ++rg) {
            float m = fmaxf(fmaxf(acc[0][rg], acc[1][rg]), fmaxf(acc[2][rg], acc[3][rg]));
            m = dppmax16(m);                     // uniform within 16-lane group
            rmax[rg] = fmaxf(rmax[rg], m);
            const float thr = rmax[rg] - 1.6f;   // slack covers bf16 screen error
            if (m > thr) {                       // tile holds a candidate for this group
                const int row = wrow0 + ag * 4 + rg;
                #pragma unroll
                for (int ct = 0; ct < 4; ++ct) {
                    const bool p = acc[ct][rg] > thr;
                    const unsigned long long ball = __ballot(p) & grpmask;
                    if (ball) {
                        const int rank = (int)__popcll(ball & lowmask);
                        if (p && base[rg] + rank < CAP)
                            CIDX[row * CAP + base[rg] + rank] =
                                (unsigned short)((t << 6) + ct * 16 + l15);
                        base[rg] += (int)__popcll(ball);
                    }
                }
            }
        }
        // counted-vmcnt barrier: own t+1 loads done; t+2 loads stay in flight
        if (t + 2 < NTILE) {
            asm volatile("s_waitcnt vmcnt(4)" ::: "memory");
            __builtin_amdgcn_s_barrier();
        } else if (t + 2 == NTILE) {
            asm volatile("s_waitcnt vmcnt(0)" ::: "memory");
            __builtin_amdgcn_s_barrier();
        }                                        // last iter: no barrier needed
        if (++bufc == 3) bufc = 0;
    }

    // publish counts
    #pragma unroll
    for (int rg = 0; rg < 4; ++rg) {
        if (l15 == 0) {
            CNT[wrow0 + ag * 4 + rg] = base[rg];
            if (base[rg] > CAP) *POVF = 1;
        }
    }
    __syncthreads();

    // ---------------- exact fp32 recompute of stored candidates ----------------
    int c = 0;
    if (lane < 16) {
        const int cc = CNT[wrow0 + lane];
        c = cc > CAP ? CAP : cc;
    }
    int x = c;
    #pragma unroll
    for (int off = 1; off < 16; off <<= 1) {
        const int v = __shfl_up(x, off);
        if ((lane & 15) >= off) x += v;
    }
    const int pfx = x - c;
    const int total = __shfl(x, 15);
    if (lane < 16)
        for (int i = 0; i < c; ++i)
            SLOT[wid * (16 * CAP) + pfx + i] = (unsigned short)((lane << 8) | i);
    __syncthreads();

    {
        const float* Qb = Q + (size_t)(b * TT + t0 + wrow0) * DD;
        const float* Kb = Kf + (size_t)b * TT * DD;
        for (int bs = 0; bs < total; bs += 8) {
            float4 qv[8], kv[8];
            int rl[8], ii[8];
            #pragma unroll
            for (int u = 0; u < 8; ++u) {
                const int s = bs + u;
                const int e = (s < total) ? (int)SLOT[wid * (16 * CAP) + s] : 0;
                rl[u] = e >> 8; ii[u] = e & 255;
                const int col = (s < total) ? (int)CIDX[(wrow0 + rl[u]) * CAP + ii[u]] : 0;
                qv[u] = *(const float4*)(Qb + (size_t)rl[u] * DD + lane * 4);
                kv[u] = *(const float4*)(Kb + (size_t)col * DD + lane * 4);
            }
            float sm[8];
            #pragma unroll
            for (int u = 0; u < 8; ++u) {
                float d = qv[u].x * kv[u].x;
                d = fmaf(qv[u].y, kv[u].y, d);
                d = fmaf(qv[u].z, kv[u].z, d);
                d = fmaf(qv[u].w, kv[u].w, d);
                sm[u] = d;
            }
            #pragma unroll
            for (int off = 32; off; off >>= 1)
                #pragma unroll
                for (int u = 0; u < 8; ++u) sm[u] += __shfl_xor(sm[u], off);
            #pragma unroll
            for (int u = 0; u < 8; ++u)
                if (lane == u && bs + u < total)
                    CVAL[(wrow0 + rl[u]) * CAP + ii[u]] = 0.5f * sm[u];
        }
    }
    __syncthreads();

    // ---------------- slow path (CAP overflow; ~never) ----------------
    if (*POVF) {
        if (wid == 0) {
            float* fbz = (float*)smem;          // staging buffers are dead
            for (int r = 0; r < RQB; ++r) {
                if (CNT[r] <= CAP) continue;
                const float* qr = Q + (size_t)(b * TT + t0 + r) * DD;
                const float* Kb = Kf + (size_t)b * TT * DD;
                for (int cc2 = lane; cc2 < TT; cc2 += 64) {
                    const float* kr = Kb + (size_t)cc2 * DD;
                    float a = 0.0f;
                    for (int d = 0; d < DD; ++d) a = fmaf(qr[d], kr[d], a);
                    fbz[cc2] = 0.5f * a;
                }
                __threadfence_block();
                float m = -3.402823466e38f;
                for (int cc2 = lane; cc2 < TT; cc2 += 64) m = fmaxf(m, fbz[cc2]);
                #pragma unroll
                for (int off = 32; off; off >>= 1) m = fmaxf(m, __shfl_xor(m, off));
                float lo = m - 1.0f, hi = m, tau;
                for (int it = 0; it < NITER; ++it) {
                    tau = 0.5f * (lo + hi);
                    float s = 0.0f;
                    for (int cc2 = lane; cc2 < TT; cc2 += 64) {
                        const float tt2 = fmaxf(fbz[cc2] - tau, 0.0f);
                        s = fmaf(tt2, tt2, s);
                    }
                    #pragma unroll
                    for (int off = 32; off; off >>= 1) s += __shfl_xor(s, off);
                    const bool gt = s > 1.0f;
                    lo = gt ? tau : lo;
                    hi = gt ? hi : tau;
                }
                tau = 0.5f * (lo + hi);
                float ssum = 0.0f;
                for (int cc2 = lane; cc2 < TT; cc2 += 64) {
                    const float tt2 = fmaxf(fbz[cc2] - tau, 0.0f);
                    ssum = fmaf(tt2, tt2, ssum);
                }
                #pragma unroll
                for (int off = 32; off; off >>= 1) ssum += __shfl_xor(ssum, off);
                const float inv = 1.0f / ssum;
                const int d4 = lane * 4;
                float4 o = make_float4(0.f, 0.f, 0.f, 0.f);
                for (int s = 0; s < TT; ++s) {
                    const float tt2 = fmaxf(fbz[s] - tau, 0.0f);
                    const float w = tt2 * tt2 * inv;
                    if (w > 0.0f) {
                        const float4 v = *(const float4*)(V + ((size_t)b * TT + s) * DD + d4);
                        o.x = fmaf(w, v.x, o.x); o.y = fmaf(w, v.y, o.y);
                        o.z = fmaf(w, v.z, o.z); o.w = fmaf(w, v.w, o.w);
                    }
                }
                *(float4*)(Out + ((size_t)(b * TT + t0 + r)) * DD + d4) = o;
                if (lane == 0) CNT[r] = -1;
                __threadfence_block();
            }
        }
        __syncthreads();
    }

    // ---------------- scalar per-lane tau + weights (lane r owns row wrow0+r) ----------------
    {
        const int myrow = wrow0 + (lane & 15);        // lanes 16+ duplicate (benign)
        const int nRaw = CNT[myrow];
        const int n = (nRaw < 0) ? 0 : (nRaw > CAP ? CAP : nRaw);
        float cvr[CAP];
        #pragma unroll
        for (int i = 0; i < CAP; ++i)
            cvr[i] = (i < n) ? CVAL[myrow * CAP + i] : -3.0e30f;
        float emax = cvr[0];
        #pragma unroll
        for (int i = 1; i < CAP; ++i) emax = fmaxf(emax, cvr[i]);
        float lo = emax - 1.0f, hi = emax;
        for (int it = 0; it < NITER; ++it) {
            const float tau = 0.5f * (lo + hi);
            float s = 0.0f;
            #pragma unroll
            for (int i = 0; i < CAP; ++i) {
                const float tt2 = fmaxf(cvr[i] - tau, 0.0f);
                s = fmaf(tt2, tt2, s);
            }
            const bool gt = s > 1.0f;
            lo = gt ? tau : lo;
            hi = gt ? hi : tau;
        }
        const float tau = 0.5f * (lo + hi);
        float ssum = 0.0f;
        #pragma unroll
        for (int i = 0; i < CAP; ++i) {
            const float tt2 = fmaxf(cvr[i] - tau, 0.0f);
            ssum = fmaf(tt2, tt2, ssum);
        }
        const float inv = 1.0f / ssum;                // valid rows: ssum > 0
        if (lane < 16 && n > 0) {
            for (int i = 0; i < n; ++i) {
                const float tt2 = fmaxf(cvr[i] - tau, 0.0f);
                CVAL[myrow * CAP + i] = tt2 * tt2 * inv;   // normalized weight
            }
        }
    }

    // ---------------- sparse PV via broadcast LDS reads ----------------
    const float* Vb = V + (size_t)b * TT * DD;
    for (int j = 0; j < 16; ++j) {
        const int row = wrow0 + j;
        const int n = CNT[row];
        if (n < 0) continue;                   // slow path handled
        const int d4 = lane * 4;
        float4 o = make_float4(0.f, 0.f, 0.f, 0.f);
        for (int i = 0; i < n; ++i) {
            const float wi = CVAL[row * CAP + i];    // LDS broadcast (uniform addr)
            if (wi > 0.0f) {
                const int si = (int)CIDX[row * CAP + i];
                const float4 v = *(const float4*)(Vb + (size_t)si * DD + d4);
                o.x = fmaf(wi, v.x, o.x); o.y = fmaf(wi, v.y, o.y);
                o.z = fmaf(wi, v.z, o.z); o.w = fmaf(wi, v.w, o.w);
            }
        }
        *(float4*)(Out + ((size_t)(b * TT + t0 + row)) * DD + d4) = o;
    }
}

// ---------------- round-1 kernel kept as ws-size fallback ----------------
#define DOT4(A, Kv, Qv) \
    A = fmaf((Qv).x, (Kv).x, fmaf((Qv).y, (Kv).y, fmaf((Qv).z, (Kv).z, fmaf((Qv).w, (Kv).w, (A)))))

__launch_bounds__(256, 2)
__global__ void entmax_fallback_kernel(const float* __restrict__ Q,
                                       const float* __restrict__ V,
                                       const float* __restrict__ K,
                                       float* __restrict__ Out) {
    extern __shared__ float zshf[];
    const int tid = threadIdx.x;
    const int b   = blockIdx.x >> 8;
    const int t0  = (blockIdx.x & 255) * 8;
    const float* Qb = Q + ((size_t)b * TT + t0) * DD;
    const float* Kb = K + (size_t)b * TT * DD;
    const float* Vb = V + (size_t)b * TT * DD;
    for (int g = 0; g < 2; ++g) {
        const int c0 = (g << 10) + tid;
        const float* k0 = Kb + (size_t)c0 * DD;
        float4 acc[8];
        #pragma unroll
        for (int r = 0; r < 8; ++r) acc[r] = make_float4(0.f, 0.f, 0.f, 0.f);
        for (int d = 0; d < DD; d += 4) {
            const float4 ka = *(const float4*)(k0 + d);
            const float4 kb = *(const float4*)(k0 + 256 * DD + d);
            const float4 kc = *(const float4*)(k0 + 512 * DD + d);
            const float4 kd = *(const float4*)(k0 + 768 * DD + d);
            #pragma unroll
            for (int r = 0; r < 8; ++r) {
                const float4 qv = *(const float4*)(Qb + r * DD + d);
                DOT4(acc[r].x, ka, qv); DOT4(acc[r].y, kb, qv);
                DOT4(acc[r].z, kc, qv); DOT4(acc[r].w, kd, qv);
            }
        }
        #pragma unroll
        for (int r = 0; r < 8; ++r) {
            zshf[r * TT + c0      ] = 0.5f * acc[r].x;
            zshf[r * TT + c0 + 256] = 0.5f * acc[r].y;
            zshf[r * TT + c0 + 512] = 0.5f * acc[r].z;
            zshf[r * TT + c0 + 768] = 0.5f * acc[r].w;
        }
    }
    __syncthreads();
    {
        const int wid = tid >> 6, lane = tid & 63;
        for (int rr = 0; rr < 2; ++rr) {
            const int r = wid * 2 + rr;
            float* z = zshf + r * TT;
            float zv[32];
            float m = -3.402823466e38f;
            #pragma unroll
            for (int j = 0; j < 32; ++j) { zv[j] = z[lane + (j << 6)]; m = fmaxf(m, zv[j]); }
            #pragma unroll
            for (int off = 32; off; off >>= 1) m = fmaxf(m, __shfl_xor(m, off));
            float lo = m - 1.0f, hi = m;
            for (int it = 0; it < NITER; ++it) {
                const float tau = 0.5f * (lo + hi);
                float s = 0.f;
                #pragma unroll
                for (int j = 0; j < 32; ++j) { float t = fmaxf(zv[j] - tau, 0.f); s = fmaf(t, t, s); }
                #pragma unroll
                for (int off = 32; off; off >>= 1) s += __shfl_xor(s, off);
                const bool gt = (s - 1.0f) > 0.0f;
                lo = gt ? tau : lo; hi = gt ? hi : tau;
            }
            const float tau = 0.5f * (lo + hi);
            float ssum = 0.f;
            #pragma unroll
            for (int j = 0; j < 32; ++j) { float t = fmaxf(zv[j] - tau, 0.f); ssum = fmaf(t, t, ssum); }
            #pragma unroll
            for (int off = 32; off; off >>= 1) ssum += __shfl_xor(ssum, off);
            const float inv = 1.0f / ssum;
            #pragma unroll
            for (int j = 0; j < 32; ++j) {
                float t = fmaxf(zv[j] - tau, 0.f);
                z[lane + (j << 6)] = t * t * inv;
            }
        }
    }
    __syncthreads();
    {
        const int d2 = (tid & 127) * 2;
        const int sg = tid >> 7;
        float2 acc[8];
        #pragma unroll
        for (int r = 0; r < 8; ++r) acc[r] = make_float2(0.f, 0.f);
        for (int sc = 0; sc < TT; sc += 8) {
            const int s0 = sc + sg * 4;
            float4 w4[8];
            #pragma unroll
            for (int r = 0; r < 8; ++r) w4[r] = *(const float4*)&zshf[r * TT + s0];
            #pragma unroll
            for (int js = 0; js < 4; ++js) {
                const float2 v = *(const float2*)(Vb + (size_t)(s0 + js) * DD + d2);
                #pragma unroll
                for (int r = 0; r < 8; ++r) {
                    const float wv = (js == 0) ? w4[r].x : (js == 1) ? w4[r].y
                                   : (js == 2) ? w4[r].z : w4[r].w;
                    acc[r].x = fmaf(wv, v.x, acc[r].x);
                    acc[r].y = fmaf(wv, v.y, acc[r].y);
                }
            }
        }
        __syncthreads();
        float* part = zshf;
        if (sg == 1) {
            #pragma unroll
            for (int r = 0; r < 8; ++r) *(float2*)&part[r * DD + d2] = acc[r];
        }
        __syncthreads();
        if (sg == 0) {
            #pragma unroll
            for (int r = 0; r < 8; ++r) {
                const float2 p = *(const float2*)&part[r * DD + d2];
                float2 o; o.x = acc[r].x + p.x; o.y = acc[r].y + p.y;
                *(float2*)&Out[((size_t)b * TT + t0 + r) * DD + d2] = o;
            }
        }
    }
}

extern "C" void kernel_launch(void* const* d_in, const int* in_sizes, int n_in,
                              void* d_out, int out_size, void* d_ws, size_t ws_size,
                              hipStream_t stream) {
    const float* Q = (const float*)d_in[0];   // query
    const float* V = (const float*)d_in[1];   // value (dict order!)
    const float* K = (const float*)d_in[2];   // key
    float* Out = (float*)d_out;
    const int B = in_sizes[0] / (TT * DD);
    const size_t NE = (size_t)B * TT * DD;
    const size_t need = NE * 2;               // Kh bf16

    if (ws_size < need) {                     // defensive fallback (round-1 kernel)
        entmax_fallback_kernel<<<dim3(B * (TT / 8)), 256, 8 * TT * sizeof(float), stream>>>(
            Q, V, K, Out);
        return;
    }

    unsigned short* Kh = (unsigned short*)d_ws;
    split_k_kernel<<<2048, 256, 0, stream>>>(K, Kh, (int)(NE / 4));

    const int nwg = B * (TT / RQB);           // 256 -> 1 block/CU, 8 waves
    (void)hipFuncSetAttribute((const void*)entmax_screen_kernel,
                              hipFuncAttributeMaxDynamicSharedMemorySize, LDS_SZ);
    entmax_screen_kernel<<<dim3(nwg), NT, LDS_SZ, stream>>>(Q, Kh, K, V, Out, nwg);
}